// Round 11
// baseline (404.143 us; speedup 1.0000x reference)
//
#include <hip/hip_runtime.h>
#include <hip/hip_bf16.h>

// QuantisedMonDEQ: n=512, d=784, B=128, C=10. All inputs/outputs float32.
// z_{t+1} = relu(0.5 z + 0.5 (Wq z + Ux)), ~40 iters; logits = z*^T Wc^T + bc.
//
// ONE dispatch: 8 blocks x 512 threads, block owns 16 batch cols.
// Phases: (A) block-local max|W|,|U|,|b| scan  (B) stage x hi/lo bf16 in LDS
// (C) Ux via bf16 MFMA  (D) quantize W -> int8 Q in MFMA-A fragment order:
//     3/8 k-chunks into LDS (96 KB), 5/8 into per-block ws region (streamed
//     from XCD L2 each iter -- residency via pins proved impossible, R9/R10
//     spilled; streaming 160 KB/iter ~ 2560 cy is the honest cost)
// (E) C-finalize + z1=relu(0.5 Ux)  (F) 37-iter int8-MFMA loop, z as hi/lo
//     int8 planes in fragment order (LDS addr = 16*lane, conflict-free)
// (G) logits from register z. No pins, no residency assumptions.
//   Q.v = 256*(Q.hi) + Q.lo' + 128*rowsum(Q), rowsum folded into C.
//   First 25 iters hi-plane only; last 12 both planes (~fp32 z).

#define N_DIM 512
#define D_DIM 784
#define C_DIM 10
#define QMAX 127.0f
#define TOTAL_ITERS 38
#define LO_ITERS 12
#define MT 4            // 16-row M-tiles per wave (8 waves x 64 rows)
#define LDS_KC 3        // k-chunks of Q resident in LDS
#define STR_KC 5        // k-chunks streamed from ws (L2)

typedef int    i32x4  __attribute__((ext_vector_type(4)));
typedef float  f32x4  __attribute__((ext_vector_type(4)));
typedef __bf16 bf16x8 __attribute__((ext_vector_type(8)));

__device__ __forceinline__ void pack_planes(float y0, float y1, float y2, float y3,
                                            unsigned* hi, unsigned* lo) {
    int p01, p23;
    asm("v_cvt_pknorm_i16_f32 %0, %1, %2" : "=v"(p01) : "v"(y0), "v"(y1));
    asm("v_cvt_pknorm_i16_f32 %0, %1, %2" : "=v"(p23) : "v"(y2), "v"(y3));
    *hi = __builtin_amdgcn_perm((unsigned)p23, (unsigned)p01, 0x07050301u);
    *lo = __builtin_amdgcn_perm((unsigned)p23, (unsigned)p01, 0x06040200u) ^ 0x80808080u;
}

__global__ __launch_bounds__(512, 2) void solve_kernel(const float* __restrict__ W,
                                                       const float* __restrict__ U,
                                                       const float* __restrict__ b,
                                                       const float* __restrict__ x,
                                                       const float* __restrict__ Wc,
                                                       const float* __restrict__ bc,
                                                       signed char* __restrict__ qws,
                                                       float* __restrict__ out) {
    // regA aliases: [phase B/C] x hi/lo staging | [D..F] Q LDS chunks (96 KB)
    //               [G] WcS (20 KB) + redS (20 KB)
    __shared__ __align__(16) unsigned char regA[98304];
    __shared__ signed char zh[2][8192];   // [buf][kc*1024 + lane*16 + j]
    __shared__ signed char zl[2][8192];
    __shared__ float rsS[N_DIM];          // maxabs scratch, then rowsum
    __shared__ float bqS[N_DIM];
    __shared__ float scS[3];

    const int t = threadIdx.x;
    const int wave = t >> 6, lane = t & 63;
    const int m = lane & 15, quad = lane >> 4;
    const int c0 = blockIdx.x * 16;
    const int rowbase = wave * 64;
    signed char* qs = qws + blockIdx.x * (STR_KC * 32768);

    // ---- phase A: block-local max|.| (redundant per block; no extra dispatch) ----
    {
        float mW = 0.f, mU = 0.f, mB = 0.f;
        const float4* W4 = (const float4*)W;
        for (int i = t; i < N_DIM * N_DIM / 4; i += 512) {
            float4 v = W4[i];
            mW = fmaxf(mW, fmaxf(fmaxf(fabsf(v.x), fabsf(v.y)), fmaxf(fabsf(v.z), fabsf(v.w))));
        }
        const float4* U4 = (const float4*)U;
        for (int i = t; i < N_DIM * D_DIM / 4; i += 512) {
            float4 v = U4[i];
            mU = fmaxf(mU, fmaxf(fmaxf(fabsf(v.x), fabsf(v.y)), fmaxf(fabsf(v.z), fabsf(v.w))));
        }
        if (t < N_DIM / 4) {
            float4 v = ((const float4*)b)[t];
            mB = fmaxf(fmaxf(fabsf(v.x), fabsf(v.y)), fmaxf(fabsf(v.z), fabsf(v.w)));
        }
#pragma unroll
        for (int s = 1; s < 64; s <<= 1) {
            mW = fmaxf(mW, __shfl_xor(mW, s));
            mU = fmaxf(mU, __shfl_xor(mU, s));
            mB = fmaxf(mB, __shfl_xor(mB, s));
        }
        if (lane == 0) { rsS[wave] = mW; rsS[8 + wave] = mU; rsS[16 + wave] = mB; }
        __syncthreads();
        if (t == 0) {
            float aW = 0.f, aU = 0.f, aB = 0.f;
            for (int i = 0; i < 8; ++i) {
                aW = fmaxf(aW, rsS[i]); aU = fmaxf(aU, rsS[8 + i]); aB = fmaxf(aB, rsS[16 + i]);
            }
            scS[0] = aW * (1.0f / QMAX); scS[1] = aU * (1.0f / QMAX); scS[2] = aB * (1.0f / QMAX);
        }
        __syncthreads();
    }
    const float sW = scS[0], sU = scS[1], sb = scS[2];
    const float invW = 1.0f / sW, invU = 1.0f / sU;
    const float sWv = sW * (16.0f / 32767.0f);
    const float K16 = 0.03125f;                  // 0.5/16
    const float KH = K16 * sWv * 256.0f;
    const float KL = K16 * sWv;
    const float KL128 = KL * 128.0f;

    // ---- phase B: stage x hi/lo (bf16, MFMA-B layout) + bq ----
    __bf16* xhS = (__bf16*)regA;                 // 12800 elems (25600 B)
    __bf16* xlS = (__bf16*)(regA + 28672);       // 12800 elems
    for (int rr = 0; rr < 16; ++rr) {
        for (int k = t; k < D_DIM; k += 512) {
            float xv = x[(c0 + rr) * D_DIM + k];
            __bf16 h = (__bf16)xv;
            int idx = ((k >> 5) * 4 + ((k >> 3) & 3)) * 128 + rr * 8 + (k & 7);
            xhS[idx] = h;
            xlS[idx] = (__bf16)(xv - (float)h);
        }
    }
    for (int i = t; i < 256; i += 512) {   // zero pad k in [784,800)
        int k = 784 + (i & 15), rr = i >> 4;
        int idx = ((k >> 5) * 4 + ((k >> 3) & 3)) * 128 + rr * 8 + (k & 7);
        xhS[idx] = (__bf16)0.0f;
        xlS[idx] = (__bf16)0.0f;
    }
    bqS[t] = rintf(b[t] / sb) * sb;
    __syncthreads();

    // ---- phase C: Ux via bf16 MFMA (Uq exact bf16; x hi/lo) ----
    f32x4 uacc[MT] = {};
#pragma unroll 2
    for (int kc = 0; kc < 25; ++kc) {
        bf16x8 bh = *(const bf16x8*)&xhS[kc * 512 + quad * 128 + m * 8];
        bf16x8 bl = *(const bf16x8*)&xlS[kc * 512 + quad * 128 + m * 8];
#pragma unroll
        for (int ti = 0; ti < MT; ++ti) {
            bf16x8 au;
            if (kc < 24 || quad < 2) {
                const float* up = U + (rowbase + ti * 16 + m) * D_DIM + kc * 32 + quad * 8;
                float4 u0 = *(const float4*)up;
                float4 u1 = *(const float4*)(up + 4);
                au[0] = (__bf16)rintf(u0.x * invU); au[1] = (__bf16)rintf(u0.y * invU);
                au[2] = (__bf16)rintf(u0.z * invU); au[3] = (__bf16)rintf(u0.w * invU);
                au[4] = (__bf16)rintf(u1.x * invU); au[5] = (__bf16)rintf(u1.y * invU);
                au[6] = (__bf16)rintf(u1.z * invU); au[7] = (__bf16)rintf(u1.w * invU);
            } else {
#pragma unroll
                for (int j = 0; j < 8; ++j) au[j] = (__bf16)0.0f;
            }
            uacc[ti] = __builtin_amdgcn_mfma_f32_16x16x32_bf16(au, bh, uacc[ti], 0, 0, 0);
            uacc[ti] = __builtin_amdgcn_mfma_f32_16x16x32_bf16(au, bl, uacc[ti], 0, 0, 0);
        }
    }
    __syncthreads();   // done with x staging; regA becomes Q LDS storage

    // ---- phase D: quantize W -> Q int8 frags: 3 kc -> LDS, 5 kc -> ws ----
    {
        float rsum[MT] = {0.f, 0.f, 0.f, 0.f};
#pragma unroll
        for (int ti = 0; ti < MT; ++ti) {
#pragma unroll
            for (int kc = 0; kc < 8; ++kc) {
                const float* wp = W + (rowbase + ti * 16 + m) * N_DIM + kc * 64 + quad * 16;
                i32x4 av;
#pragma unroll
                for (int s = 0; s < 4; ++s) {
                    float4 w4 = *(const float4*)(wp + s * 4);
                    float f0 = rintf(w4.x * invW), f1 = rintf(w4.y * invW);
                    float f2 = rintf(w4.z * invW), f3 = rintf(w4.w * invW);
                    rsum[ti] += (f0 + f1) + (f2 + f3);
                    av[s] = ((int)f0 & 255) | (((int)f1 & 255) << 8) |
                            (((int)f2 & 255) << 16) | ((int)f3 << 24);
                }
                if (kc < LDS_KC)
                    *(i32x4*)&regA[(((kc * 8 + wave) * MT + ti) << 10) + lane * 16] = av;
                else
                    *(i32x4*)&qs[((((kc - LDS_KC) * 8 + wave) * MT + ti) << 10) + lane * 16] = av;
            }
        }
#pragma unroll
        for (int ti = 0; ti < MT; ++ti) {
            rsum[ti] += __shfl_xor(rsum[ti], 16);
            rsum[ti] += __shfl_xor(rsum[ti], 32);
            if (quad == 0) rsS[rowbase + ti * 16 + m] = rsum[ti];
        }
    }
    __syncthreads();

    // ---- phase E: C-finalize + z1 = relu(0.5 Ux) ----
    float yv[MT][4], Cf[MT][4];
#pragma unroll
    for (int ti = 0; ti < MT; ++ti) {
        const int row0 = rowbase + ti * 16 + quad * 4;
#pragma unroll
        for (int r = 0; r < 4; ++r) {
            float Uxval = fmaf(sU, uacc[ti][r], bqS[row0 + r]);
            Cf[ti][r] = fmaf(KL128, rsS[row0 + r], K16 * Uxval);
            yv[ti][r] = fmaxf(K16 * Uxval, 0.0f);
        }
        unsigned hw, lw;
        pack_planes(yv[ti][0], yv[ti][1], yv[ti][2], yv[ti][3], &hw, &lw);
        *(unsigned*)&zh[0][wave * 1024 + ti * 256 + m * 16 + quad * 4] = hw;
    }
    __syncthreads();

    // ---- phase F: fixed-point loop ----
    int cur = 0;
#pragma unroll 1
    for (int it = 1; it < TOTAL_ITERS; ++it) {
        const bool lo  = (it >= TOTAL_ITERS - LO_ITERS);
        const bool wlo = (it >= TOTAL_ITERS - LO_ITERS - 1);
        // issue streamed A loads early (20 x dwordx4, coalesced 1KB/wave)
        i32x4 As[STR_KC][MT];
#pragma unroll
        for (int s = 0; s < STR_KC; ++s)
#pragma unroll
            for (int ti = 0; ti < MT; ++ti)
                As[s][ti] = *(const i32x4*)&qs[(((s * 8 + wave) * MT + ti) << 10) + lane * 16];
        i32x4 acch[MT] = {};
        i32x4 accl[MT] = {};
#pragma unroll
        for (int kc = 0; kc < LDS_KC; ++kc) {
            i32x4 bh = *(const i32x4*)&zh[cur][(kc << 10) + lane * 16];
            i32x4 bl;
            if (lo) bl = *(const i32x4*)&zl[cur][(kc << 10) + lane * 16];
#pragma unroll
            for (int ti = 0; ti < MT; ++ti) {
                i32x4 a = *(const i32x4*)&regA[(((kc * 8 + wave) * MT + ti) << 10) + lane * 16];
                acch[ti] = __builtin_amdgcn_mfma_i32_16x16x64_i8(a, bh, acch[ti], 0, 0, 0);
                if (lo) accl[ti] = __builtin_amdgcn_mfma_i32_16x16x64_i8(a, bl, accl[ti], 0, 0, 0);
            }
        }
#pragma unroll
        for (int s = 0; s < STR_KC; ++s) {
            const int kc = LDS_KC + s;
            i32x4 bh = *(const i32x4*)&zh[cur][(kc << 10) + lane * 16];
            i32x4 bl;
            if (lo) bl = *(const i32x4*)&zl[cur][(kc << 10) + lane * 16];
#pragma unroll
            for (int ti = 0; ti < MT; ++ti) {
                acch[ti] = __builtin_amdgcn_mfma_i32_16x16x64_i8(As[s][ti], bh, acch[ti], 0, 0, 0);
                if (lo) accl[ti] = __builtin_amdgcn_mfma_i32_16x16x64_i8(As[s][ti], bl, accl[ti], 0, 0, 0);
            }
        }
        const int nxt = cur ^ 1;
#pragma unroll
        for (int ti = 0; ti < MT; ++ti) {
#pragma unroll
            for (int r = 0; r < 4; ++r) {
                float base = lo ? fmaf(KL, (float)accl[ti][r], Cf[ti][r]) : Cf[ti][r];
                float u = fmaf(KH, (float)acch[ti][r], base);
                yv[ti][r] = fmaxf(fmaf(0.5f, yv[ti][r], u), 0.0f);
            }
            unsigned hw, lw;
            pack_planes(yv[ti][0], yv[ti][1], yv[ti][2], yv[ti][3], &hw, &lw);
            const int wr = wave * 1024 + ti * 256 + m * 16 + quad * 4;
            *(unsigned*)&zh[nxt][wr] = hw;
            if (wlo) *(unsigned*)&zl[nxt][wr] = lw;
        }
        __syncthreads();
        cur = nxt;
    }

    // ---- phase G: fused logits from register y (z = 16 y) ----
    {
        float* WcS  = (float*)regA;              // 5120 floats (20 KB)
        float* redS = (float*)(regA + 24576);    // 32 x 16 x 10 floats (20 KB)
        for (int i = t; i < C_DIM * N_DIM; i += 512) WcS[i] = Wc[i];
        __syncthreads();
        float p[C_DIM];
#pragma unroll
        for (int cl = 0; cl < C_DIM; ++cl) p[cl] = 0.0f;
#pragma unroll
        for (int ti = 0; ti < MT; ++ti) {
            const int row0 = rowbase + ti * 16 + quad * 4;
#pragma unroll
            for (int r = 0; r < 4; ++r) {
                float zv = 16.0f * yv[ti][r];
#pragma unroll
                for (int cl = 0; cl < C_DIM; ++cl)
                    p[cl] += zv * WcS[cl * N_DIM + row0 + r];
            }
        }
        const int grp = wave * 4 + quad;   // 0..31
#pragma unroll
        for (int cl = 0; cl < C_DIM; ++cl) redS[(grp * 16 + m) * C_DIM + cl] = p[cl];
        __syncthreads();
        for (int s = 16; s > 0; s >>= 1) {
            if (grp < s) {
#pragma unroll
                for (int cl = 0; cl < C_DIM; ++cl)
                    redS[(grp * 16 + m) * C_DIM + cl] += redS[((grp + s) * 16 + m) * C_DIM + cl];
            }
            __syncthreads();
        }
        if (t < 16 * C_DIM)
            out[(c0 + (t & 15)) * C_DIM + (t >> 4)] = redS[(t & 15) * C_DIM + (t >> 4)] + bc[t >> 4];
    }
}

extern "C" void kernel_launch(void* const* d_in, const int* in_sizes, int n_in,
                              void* d_out, int out_size, void* d_ws, size_t ws_size,
                              hipStream_t stream) {
    const float* W  = (const float*)d_in[0];
    const float* U  = (const float*)d_in[1];
    const float* b  = (const float*)d_in[2];
    const float* x  = (const float*)d_in[3];
    const float* Wc = (const float*)d_in[4];
    const float* bc = (const float*)d_in[5];
    float* out = (float*)d_out;

    signed char* qws = (signed char*)d_ws;   // 8 blocks x 160 KB = 1.31 MB

    solve_kernel<<<8, 512, 0, stream>>>(W, U, b, x, Wc, bc, qws, out);
}

// Round 12
// 190.656 us; speedup vs baseline: 2.1197x; 2.1197x over previous
//
#include <hip/hip_runtime.h>
#include <hip/hip_bf16.h>

// QuantisedMonDEQ: n=512, d=784, B=128, C=10. All inputs/outputs float32.
// z_{t+1} = relu(0.5 z + 0.5 (Wq z + Ux)), 40 iters; logits = z*^T Wc^T + bc.
//
// 3 dispatches (R8 structure, proven 158us):
//  1) maxabs (192 blocks)  2) prep (512 blocks): W->int8 Qp8 frags + rowsum,
//  UxT via staged bf16 MFMA  3) solve (8 blocks x 512): 38-iter int8-MFMA
//  fixed point. NEW vs R8: 3/8 kc of Q copied to LDS in the prologue (96 KB),
//  5/8 streamed inline per-kc from L2 (R8's proven load-use pattern, no
//  prefetch arrays -> no VGPR cliff); z planes in MFMA-fragment order
//  (addr=16*lane, conflict-free); pknorm epilogue; shfl-based logits reduce.
//   Q.v = 256*(Q.hi) + Q.lo' + 128*rowsum(Q), rowsum folded into C.
//   First 25 iters hi-plane only; last 12 both planes (~fp32 z).

#define N_DIM 512
#define D_DIM 784
#define C_DIM 10
#define QMAX 127.0f
#define TOTAL_ITERS 38
#define LO_ITERS 12
#define MT 4            // 16-row M-tiles per wave (8 waves x 64 rows)
#define LDS_KC 3        // kc-chunks of Q resident in LDS (96 KB)
#define UPITCH 808

typedef int    i32x4  __attribute__((ext_vector_type(4)));
typedef float  f32x4  __attribute__((ext_vector_type(4)));
typedef __bf16 bf16x8 __attribute__((ext_vector_type(8)));

__device__ __forceinline__ float pscale64(const float* __restrict__ p) {
    float m = 0.0f;
#pragma unroll 16
    for (int i = 0; i < 64; ++i) m = fmaxf(m, p[i]);
    return m * (1.0f / QMAX);
}

// ---------------- per-block partial max|.| ----------------
__global__ void maxabs_kernel(const float* __restrict__ W,
                              const float* __restrict__ U,
                              const float* __restrict__ b,
                              float* __restrict__ partials) {
    const float4* src;
    int n4;
    if (blockIdx.y == 0)      { src = (const float4*)W; n4 = N_DIM * N_DIM / 4; }
    else if (blockIdx.y == 1) { src = (const float4*)U; n4 = N_DIM * D_DIM / 4; }
    else                      { src = (const float4*)b; n4 = N_DIM / 4; }
    float m = 0.0f;
    for (int i = blockIdx.x * blockDim.x + threadIdx.x; i < n4; i += gridDim.x * blockDim.x) {
        float4 v = src[i];
        m = fmaxf(m, fmaxf(fmaxf(fabsf(v.x), fabsf(v.y)), fmaxf(fabsf(v.z), fabsf(v.w))));
    }
    __shared__ float red[256];
    red[threadIdx.x] = m;
    __syncthreads();
    for (int s = 128; s > 0; s >>= 1) {
        if (threadIdx.x < s) red[threadIdx.x] = fmaxf(red[threadIdx.x], red[threadIdx.x + s]);
        __syncthreads();
    }
    if (threadIdx.x == 0) partials[blockIdx.y * 64 + blockIdx.x] = red[0];
}

// -------- prep: blocks 0..255 quantW(int8)+rowsum; 256..511 uxT (staged) --------
__global__ __launch_bounds__(256) void prep_kernel(const float* __restrict__ W,
                                                   const float* __restrict__ U,
                                                   const float* __restrict__ b,
                                                   const float* __restrict__ x,
                                                   const float* __restrict__ partials,
                                                   int* __restrict__ rowsum,
                                                   signed char* __restrict__ Qp8,
                                                   float* __restrict__ UxT) {
    __shared__ __bf16 uS[16][UPITCH];
    __shared__ __bf16 xhS[16][UPITCH];
    __shared__ __bf16 xlS[16][UPITCH];
    __shared__ f32x4  sacc[4][64];
    __shared__ int ls[4];
    const int t = threadIdx.x;
    if (blockIdx.x < 256) {
        const float s = pscale64(partials);
        const float inv = 1.0f / s;
        int idx = blockIdx.x * 256 + t;            // float4 index into W
        float4 w = ((const float4*)W)[idx];
        int k = (idx << 2) & (N_DIM - 1);
        int r = (idx << 2) >> 9;
        int q0 = (int)rintf(w.x * inv);
        int q1 = (int)rintf(w.y * inv);
        int q2 = (int)rintf(w.z * inv);
        int q3 = (int)rintf(w.w * inv);
        char4 c;
        c.x = (signed char)q0; c.y = (signed char)q1;
        c.z = (signed char)q2; c.w = (signed char)q3;
        int kc = k >> 6, q = (k >> 4) & 3, jj = k & 15;
        *(char4*)&Qp8[((kc << 9) + r) * 64 + q * 16 + jj] = c;
        int psum = q0 + q1 + q2 + q3;
#pragma unroll
        for (int s2 = 1; s2 < 64; s2 <<= 1) psum += __shfl_xor(psum, s2);
        if ((t & 63) == 0) ls[t >> 6] = psum;
        __syncthreads();
        if (t == 0) {
            rowsum[2 * blockIdx.x]     = ls[0] + ls[1];
            rowsum[2 * blockIdx.x + 1] = ls[2] + ls[3];
        }
    } else {
        const float sU = pscale64(partials + 64);
        const float invU = 1.0f / sU;
        const float sb = pscale64(partials + 128);
        const int bx = blockIdx.x - 256;           // 0..255
        const int i0 = (bx >> 3) * 16;             // U-row tile base
        const int c0 = (bx & 7) * 16;              // batch-col tile base
        for (int r = 0; r < 16; ++r) {
            for (int k = t; k < D_DIM; k += 256) {
                float uv = U[(i0 + r) * D_DIM + k];
                uS[r][k] = (__bf16)rintf(uv * invU);
                float xv = x[(c0 + r) * D_DIM + k];
                __bf16 h = (__bf16)xv;
                xhS[r][k] = h;
                xlS[r][k] = (__bf16)(xv - (float)h);
            }
        }
        for (int i = t; i < 16 * 16; i += 256) {
            int r = i >> 4, k = D_DIM + (i & 15);
            uS[r][k] = (__bf16)0.0f; xhS[r][k] = (__bf16)0.0f; xlS[r][k] = (__bf16)0.0f;
        }
        __syncthreads();
        const int wave = t >> 6, lane = t & 63;
        const int m = lane & 15, quad = lane >> 4;
        f32x4 acc = {};
        for (int kc = wave; kc < 25; kc += 4) {
            bf16x8 a  = *(const bf16x8*)&uS[m][kc * 32 + (quad << 3)];
            bf16x8 bh = *(const bf16x8*)&xhS[m][kc * 32 + (quad << 3)];
            bf16x8 bl = *(const bf16x8*)&xlS[m][kc * 32 + (quad << 3)];
            acc = __builtin_amdgcn_mfma_f32_16x16x32_bf16(a, bh, acc, 0, 0, 0);
            acc = __builtin_amdgcn_mfma_f32_16x16x32_bf16(a, bl, acc, 0, 0, 0);
        }
        sacc[wave][lane] = acc;
        __syncthreads();
        if (wave == 0) {
            f32x4 s0 = sacc[0][lane], s1 = sacc[1][lane];
            f32x4 s2 = sacc[2][lane], s3 = sacc[3][lane];
            const int row0 = i0 + (quad << 2);
            f32x4 o;
#pragma unroll
            for (int r = 0; r < 4; ++r)
                o[r] = sU * (s0[r] + s1[r] + s2[r] + s3[r])
                     + rintf(b[row0 + r] / sb) * sb;
            *(f32x4*)&UxT[(c0 + m) * N_DIM + row0] = o;
        }
    }
}

// pack 4 y-values into hi and lo int8-plane dwords
__device__ __forceinline__ void pack_planes(float y0, float y1, float y2, float y3,
                                            unsigned* hi, unsigned* lo) {
    int p01, p23;
    asm("v_cvt_pknorm_i16_f32 %0, %1, %2" : "=v"(p01) : "v"(y0), "v"(y1));
    asm("v_cvt_pknorm_i16_f32 %0, %1, %2" : "=v"(p23) : "v"(y2), "v"(y3));
    *hi = __builtin_amdgcn_perm((unsigned)p23, (unsigned)p01, 0x07050301u);
    *lo = __builtin_amdgcn_perm((unsigned)p23, (unsigned)p01, 0x06040200u) ^ 0x80808080u;
}

// ---------------- int8-MFMA solve + logits ----------------
__global__ __launch_bounds__(512, 2) void solve_kernel(const signed char* __restrict__ Qp8,
                                                       const float* __restrict__ UxT,
                                                       const float* __restrict__ partials,
                                                       const int* __restrict__ rowsum,
                                                       const float* __restrict__ Wc,
                                                       const float* __restrict__ bc,
                                                       float* __restrict__ out) {
    __shared__ __align__(16) signed char ldsA[LDS_KC * 32768];   // 96 KB
    __shared__ signed char zh[2][8192];   // [buf][kc*1024 + lane*16 + j]
    __shared__ signed char zl[2][8192];
    __shared__ float redL[8][16][C_DIM];  // 5 KB

    const int t = threadIdx.x;
    const int wave = t >> 6, lane = t & 63;
    const int m = lane & 15, quad = lane >> 4;
    const int c0 = blockIdx.x * 16;
    const int rowbase = wave * 64;

    const float sW = pscale64(partials);
    const float sWv = sW * (16.0f / 32767.0f);
    const float K16 = 0.03125f;                  // 0.5/16
    const float KH = K16 * sWv * 256.0f;
    const float KL = K16 * sWv;
    const float KL128 = KL * 128.0f;

    // ---- prologue: LDS-A fill for kc 0..LDS_KC-1 (coalesced dwordx4) ----
    const signed char* qA = Qp8 + (rowbase + m) * 64 + (quad << 4);
    const int lA = wave * 4096 + (lane << 4);
#pragma unroll
    for (int kc = 0; kc < LDS_KC; ++kc)
#pragma unroll
        for (int ti = 0; ti < MT; ++ti)
            *(i32x4*)&ldsA[kc * 32768 + lA + ti * 1024] =
                *(const i32x4*)(qA + kc * 32768 + ti * 1024);

    // ---- per-lane C-finalize + z1 = relu(0.5 Ux) (y = z/16 domain) ----
    float yv[MT][4], Cf[MT][4];
#pragma unroll
    for (int ti = 0; ti < MT; ++ti) {
        const int row0 = rowbase + ti * 16 + (quad << 2);
#pragma unroll
        for (int r = 0; r < 4; ++r) {
            float Uxval = UxT[(c0 + m) * N_DIM + row0 + r];
            Cf[ti][r] = fmaf(KL128, (float)rowsum[row0 + r], K16 * Uxval);
            yv[ti][r] = fmaxf(K16 * Uxval, 0.0f);
        }
        unsigned hw, lw;
        pack_planes(yv[ti][0], yv[ti][1], yv[ti][2], yv[ti][3], &hw, &lw);
        *(unsigned*)&zh[0][wave * 1024 + ti * 256 + m * 16 + quad * 4] = hw;
    }
    __syncthreads();

    // ---- fixed-point loop ----
    int cur = 0;
#pragma unroll 1
    for (int it = 1; it < TOTAL_ITERS; ++it) {
        const bool lo  = (it >= TOTAL_ITERS - LO_ITERS);
        const bool wlo = (it >= TOTAL_ITERS - LO_ITERS - 1);
        i32x4 acch[MT] = {};
        i32x4 accl[MT] = {};
        // streamed kc (global L2, inline load-use: R8-proven, no reg cliff)
#pragma unroll
        for (int kc = LDS_KC; kc < 8; ++kc) {
            i32x4 bh = *(const i32x4*)&zh[cur][(kc << 10) + (lane << 4)];
            i32x4 bl;
            if (lo) bl = *(const i32x4*)&zl[cur][(kc << 10) + (lane << 4)];
#pragma unroll
            for (int ti = 0; ti < MT; ++ti) {
                i32x4 a = *(const i32x4*)(qA + kc * 32768 + ti * 1024);
                acch[ti] = __builtin_amdgcn_mfma_i32_16x16x64_i8(a, bh, acch[ti], 0, 0, 0);
                if (lo) accl[ti] = __builtin_amdgcn_mfma_i32_16x16x64_i8(a, bl, accl[ti], 0, 0, 0);
            }
        }
        // LDS-resident kc
#pragma unroll
        for (int kc = 0; kc < LDS_KC; ++kc) {
            i32x4 bh = *(const i32x4*)&zh[cur][(kc << 10) + (lane << 4)];
            i32x4 bl;
            if (lo) bl = *(const i32x4*)&zl[cur][(kc << 10) + (lane << 4)];
#pragma unroll
            for (int ti = 0; ti < MT; ++ti) {
                i32x4 a = *(const i32x4*)&ldsA[kc * 32768 + lA + ti * 1024];
                acch[ti] = __builtin_amdgcn_mfma_i32_16x16x64_i8(a, bh, acch[ti], 0, 0, 0);
                if (lo) accl[ti] = __builtin_amdgcn_mfma_i32_16x16x64_i8(a, bl, accl[ti], 0, 0, 0);
            }
        }
        const int nxt = cur ^ 1;
#pragma unroll
        for (int ti = 0; ti < MT; ++ti) {
#pragma unroll
            for (int r = 0; r < 4; ++r) {
                float base = lo ? fmaf(KL, (float)accl[ti][r], Cf[ti][r]) : Cf[ti][r];
                float u = fmaf(KH, (float)acch[ti][r], base);
                yv[ti][r] = fmaxf(fmaf(0.5f, yv[ti][r], u), 0.0f);
            }
            unsigned hw, lw;
            pack_planes(yv[ti][0], yv[ti][1], yv[ti][2], yv[ti][3], &hw, &lw);
            const int wr = wave * 1024 + ti * 256 + m * 16 + quad * 4;
            *(unsigned*)&zh[nxt][wr] = hw;
            if (wlo) *(unsigned*)&zl[nxt][wr] = lw;
        }
        __syncthreads();
        cur = nxt;
    }

    // ---- logits from register y (z = 16 y): quad-shfl then 5 KB LDS ----
    {
        float p[C_DIM];
#pragma unroll
        for (int cl = 0; cl < C_DIM; ++cl) p[cl] = 0.0f;
#pragma unroll
        for (int ti = 0; ti < MT; ++ti) {
            const int row0 = rowbase + ti * 16 + (quad << 2);
#pragma unroll
            for (int r = 0; r < 4; ++r) {
                float zv = 16.0f * yv[ti][r];
#pragma unroll
                for (int cl = 0; cl < C_DIM; ++cl)
                    p[cl] += zv * Wc[cl * N_DIM + row0 + r];
            }
        }
#pragma unroll
        for (int cl = 0; cl < C_DIM; ++cl) {
            p[cl] += __shfl_xor(p[cl], 16);
            p[cl] += __shfl_xor(p[cl], 32);
        }
        if (quad == 0)
#pragma unroll
            for (int cl = 0; cl < C_DIM; ++cl) redL[wave][m][cl] = p[cl];
        __syncthreads();
        if (t < 16 * C_DIM) {
            int mm = t & 15, cl = t >> 4;
            float s = bc[cl];
#pragma unroll
            for (int w = 0; w < 8; ++w) s += redL[w][mm][cl];
            out[(c0 + mm) * C_DIM + cl] = s;
        }
    }
}

extern "C" void kernel_launch(void* const* d_in, const int* in_sizes, int n_in,
                              void* d_out, int out_size, void* d_ws, size_t ws_size,
                              hipStream_t stream) {
    const float* W  = (const float*)d_in[0];
    const float* U  = (const float*)d_in[1];
    const float* b  = (const float*)d_in[2];
    const float* x  = (const float*)d_in[3];
    const float* Wc = (const float*)d_in[4];
    const float* bc = (const float*)d_in[5];
    float* out = (float*)d_out;

    float* ws = (float*)d_ws;
    float* partials = ws;                               // 3*64 floats
    int* rowsum = (int*)(ws + 256);                     // 512 ints
    signed char* Qp8 = (signed char*)(ws + 256 + 512);  // 512x512 int8, [kc][r][64B]
    float* UxT = ws + 256 + 512 + (N_DIM * N_DIM / 4);  // 128x512 fp32

    maxabs_kernel<<<dim3(64, 3), 256, 0, stream>>>(W, U, b, partials);
    prep_kernel<<<512, 256, 0, stream>>>(W, U, b, x, partials, rowsum, Qp8, UxT);
    solve_kernel<<<8, 512, 0, stream>>>(Qp8, UxT, partials, rowsum, Wc, bc, out);
}